// Round 3
// baseline (211.215 us; speedup 1.0000x reference)
//
#include <hip/hip_runtime.h>
#include <stdint.h>

#define BATCH 16384
#define SDIM 512
#define ADIM 64
#define XDIM 576      // SDIM + ADIM
#define HDIM 1024
#define NQD 64
#define QED 64

typedef __attribute__((ext_vector_type(8))) short short8;
typedef __attribute__((ext_vector_type(4))) float f32x4;

static __device__ inline unsigned short f2bf(float f) {
  unsigned int u = __float_as_uint(f);
  unsigned int r = (u + 0x7fffu + ((u >> 16) & 1u)) >> 16;
  return (unsigned short)r;
}
static __device__ inline float bf2f(unsigned short u) {
  return __uint_as_float(((unsigned int)u) << 16);
}

static __device__ inline void gload_lds16(const void* g, void* l) {
  __builtin_amdgcn_global_load_lds(
      (const __attribute__((address_space(1))) uint32_t*)g,
      (__attribute__((address_space(3))) uint32_t*)l, 16, 0, 0);
}

#define FENCE() asm volatile("" ::: "memory")

// ---------------- conversion kernels ----------------

__global__ __launch_bounds__(256) void cvt_x(const float* __restrict__ st,
                                             const float* __restrict__ ac,
                                             unsigned short* __restrict__ xb) {
  const int total = BATCH * XDIM / 4;
  for (int i = blockIdx.x * blockDim.x + threadIdx.x; i < total;
       i += gridDim.x * blockDim.x) {
    const int e = i * 4;
    const int b = e / XDIM;
    const int j = e - b * XDIM;
    float4 v;
    if (j < SDIM) v = *(const float4*)(st + (size_t)b * SDIM + j);
    else          v = *(const float4*)(ac + (size_t)b * ADIM + (j - SDIM));
    ushort4 o;
    o.x = f2bf(v.x); o.y = f2bf(v.y); o.z = f2bf(v.z); o.w = f2bf(v.w);
    ((ushort4*)xb)[i] = o;
  }
}

__global__ __launch_bounds__(256) void cvt_w(const float* __restrict__ src,
                                             unsigned short* __restrict__ dst, int n4) {
  for (int i = blockIdx.x * blockDim.x + threadIdx.x; i < n4;
       i += gridDim.x * blockDim.x) {
    const float4 v = ((const float4*)src)[i];
    ushort4 o;
    o.x = f2bf(v.x); o.y = f2bf(v.y); o.z = f2bf(v.z); o.w = f2bf(v.w);
    ((ushort4*)dst)[i] = o;
  }
}

// ---------------- tau embedding head contribution (exact fp32) ----------------

__global__ void qtau_kernel(const float* __restrict__ We1, const float* __restrict__ be1,
                            const float* __restrict__ We2, const float* __restrict__ be2,
                            const float* __restrict__ Wh,  const float* __restrict__ bh,
                            float* __restrict__ qtau) {
  const int c = blockIdx.x >> 6;
  const int nq = blockIdx.x & 63;
  const int q = threadIdx.x;  // 64 threads = 1 wave
  const float tau = (float)nq / 64.0f + 0.0078125f;
  float acc = be2[c * 64 + q];
  for (int e = 0; e < 64; ++e) {
    const float t1 = fmaxf(tau * We1[c * 64 + e] + be1[c * 64 + e], 0.0f);
    acc += t1 * We2[(c * 64 + q) * 64 + e];
  }
  float v = acc * Wh[c * (HDIM + QED) + HDIM + q];
  #pragma unroll
  for (int off = 32; off; off >>= 1) v += __shfl_xor(v, off);
  if (q == 0) qtau[c * 64 + nq] = v + bh[c];
}

// ---------------- 256x256 bf16 GEMM, 3-phase/K-tile, WAR-free registers ----
// C[M,1024] = A[M,K] * W[1024,K]^T + bias, bf16 in/out, fp32 accum.
// 8 waves (2M x 4N), BK=64. Per K-tile: 3 pre-MFMA barriers + 1 boundary
// barrier (no post-MFMA barriers), counted vmcnt(4) at the boundary only.
// A-frags split a0/a1 by half, b0 parity-duplicated -> no adjacent-phase
// register WAR, so next phase's ds_reads/stages overlap the MFMA pipe drain.

template <int K>
__global__ __launch_bounds__(512, 2) void gemm256(const unsigned short* __restrict__ A,
                                                  const unsigned short* __restrict__ W,
                                                  const float* __restrict__ bias,
                                                  unsigned short* __restrict__ C) {
  constexpr int NT = K / 64;
  __shared__ unsigned short Asm[2][256][64];
  __shared__ unsigned short Bsm[2][256][64];

  const int tid  = threadIdx.x;
  const int lane = tid & 63;
  const int wave = tid >> 6;
  const int wm = wave >> 2;   // 0..1
  const int wn = wave & 3;    // 0..3

  // XCD-bijective swizzle: 256 blocks, 8 XCDs, 32 contiguous logical per XCD.
  const int L = (int)blockIdx.x;
  const int logical = (L & 7) * 32 + (L >> 3);
  const int mBase = (logical >> 2) * 256;
  const int nBase = (logical & 3) * 256;

  // staging geometry: per half-tile (128x64) each wave writes 2 x 1KB chunks
  const int c0 = wave * 2;
  const int srow  = lane >> 3;                 // 0..7 within chunk
  const int sslot = (lane & 7) ^ (lane >> 3);  // inverse-swizzled source slot

  auto stageA = [&](int buf, int h, int kt) {
    const unsigned short* s =
        A + (size_t)(mBase + h * 128 + c0 * 8 + srow) * K + kt * 64 + sslot * 8;
    gload_lds16(s, &Asm[buf][h * 128 + c0 * 8][0]);
    gload_lds16(s + (size_t)8 * K, &Asm[buf][h * 128 + c0 * 8 + 8][0]);
  };
  auto stageB = [&](int buf, int h, int kt) {
    const unsigned short* s =
        W + (size_t)(nBase + h * 128 + c0 * 8 + srow) * K + kt * 64 + sslot * 8;
    gload_lds16(s, &Bsm[buf][h * 128 + c0 * 8][0]);
    gload_lds16(s + (size_t)8 * K, &Bsm[buf][h * 128 + c0 * 8 + 8][0]);
  };

  auto ldA = [&](short8* d, int buf, int mh) {
    #pragma unroll
    for (int fm = 0; fm < 4; ++fm)
      #pragma unroll
      for (int ks = 0; ks < 2; ++ks) {
        const int r = mh * 128 + wm * 64 + fm * 16 + (lane & 15);
        const int ps = (ks * 4 + (lane >> 4)) ^ (r & 7);
        d[fm * 2 + ks] = *(const short8*)&Asm[buf][r][ps * 8];
      }
  };
  auto ldB = [&](short8* d, int buf, int nhalf) {
    #pragma unroll
    for (int fn = 0; fn < 2; ++fn)
      #pragma unroll
      for (int ks = 0; ks < 2; ++ks) {
        const int r = nhalf * 128 + wn * 32 + fn * 16 + (lane & 15);
        const int ps = (ks * 4 + (lane >> 4)) ^ (r & 7);
        d[fn * 2 + ks] = *(const short8*)&Bsm[buf][r][ps * 8];
      }
  };

  f32x4 acc[4][4][2];
  #pragma unroll
  for (int q = 0; q < 4; ++q)
    #pragma unroll
    for (int fm = 0; fm < 4; ++fm)
      #pragma unroll
      for (int fn = 0; fn < 2; ++fn) {
        f32x4 z = {0.f, 0.f, 0.f, 0.f};
        acc[q][fm][fn] = z;
      }

  auto mfmaQ = [&](f32x4 (&aq)[4][2], short8* a, short8* b) {
    #pragma unroll
    for (int fm = 0; fm < 4; ++fm)
      #pragma unroll
      for (int fn = 0; fn < 2; ++fn)
        #pragma unroll
        for (int ks = 0; ks < 2; ++ks)
          aq[fm][fn] = __builtin_amdgcn_mfma_f32_16x16x32_bf16(
              a[fm * 2 + ks], b[fn * 2 + ks], aq[fm][fn], 0, 0, 0);
  };

  short8 a0[8], a1[8], b0E[4], b0O[4], b1[4];

  // prologue: tile0 fully + Ah0(1), Bh1(1) (steady-state stream positions)
  stageA(0, 0, 0); stageA(0, 1, 0); stageB(0, 0, 0); stageB(0, 1, 0);
  if (NT > 1) { stageA(1, 0, 1); stageB(1, 1, 1); }
  FENCE();
  if (NT > 1) asm volatile("s_waitcnt vmcnt(4)" ::: "memory");
  else        asm volatile("s_waitcnt vmcnt(0)" ::: "memory");
  __builtin_amdgcn_s_barrier();
  FENCE();

  auto tile = [&](int t, short8 (&b0)[4]) {
    const int buf = t & 1;
    // phase 0: quadrant (Ah0,Bh0); stage Ah1(t+1)
    ldA(a0, buf, 0);
    ldB(b0, buf, 0);
    if (t + 1 < NT) stageA(buf ^ 1, 1, t + 1);
    FENCE(); __builtin_amdgcn_s_barrier(); FENCE();
    __builtin_amdgcn_s_setprio(1);
    mfmaQ(acc[0], a0, b0);
    __builtin_amdgcn_s_setprio(0);
    // phase 1: quadrant (Ah0,Bh1); stage Bh0(t+1)
    ldB(b1, buf, 1);
    if (t + 1 < NT) stageB(buf ^ 1, 0, t + 1);
    FENCE(); __builtin_amdgcn_s_barrier(); FENCE();
    __builtin_amdgcn_s_setprio(1);
    mfmaQ(acc[1], a0, b1);
    __builtin_amdgcn_s_setprio(0);
    // phase 2: quadrants (Ah1,Bh1) + (Ah1,Bh0); stage Ah0(t+2), Bh1(t+2)
    ldA(a1, buf, 1);
    if (t + 2 < NT) stageA(buf, 0, t + 2);
    FENCE(); __builtin_amdgcn_s_barrier(); FENCE();
    __builtin_amdgcn_s_setprio(1);
    mfmaQ(acc[2], a1, b1);
    mfmaQ(acc[3], a1, b0);
    __builtin_amdgcn_s_setprio(0);
    if (t + 2 < NT) stageB(buf, 1, t + 2);
    FENCE();
    if (t >= NT - 2) asm volatile("s_waitcnt vmcnt(0)" ::: "memory");
    else             asm volatile("s_waitcnt vmcnt(4)" ::: "memory");
    __builtin_amdgcn_s_barrier();
    FENCE();
  };

  for (int t = 0; t < NT; t += 2) {
    tile(t, b0E);
    if (t + 1 < NT) tile(t + 1, b0O);
  }

  // epilogue: bias + bf16 round + store
  const int MH[4] = {0, 0, 1, 1};
  const int NH[4] = {0, 1, 1, 0};
  #pragma unroll
  for (int q = 0; q < 4; ++q)
    #pragma unroll
    for (int fm = 0; fm < 4; ++fm)
      #pragma unroll
      for (int fn = 0; fn < 2; ++fn) {
        const int col = nBase + NH[q] * 128 + wn * 32 + fn * 16 + (lane & 15);
        const int row0 = mBase + MH[q] * 128 + wm * 64 + fm * 16 + (lane >> 4) * 4;
        const float bv = bias[col];
        #pragma unroll
        for (int j = 0; j < 4; ++j)
          C[(size_t)(row0 + j) * HDIM + col] = f2bf(acc[q][fm][fn][j] + bv);
      }
}

// ---------------- row LayerNorm + ReLU (+ optional fused head) ----------------

template <bool HEAD>
__global__ __launch_bounds__(256) void ln_head(const unsigned short* __restrict__ X,
                                               const float* __restrict__ g,
                                               const float* __restrict__ bta,
                                               unsigned short* __restrict__ Y,
                                               const float* __restrict__ Wh,
                                               const float* __restrict__ qt,
                                               float* __restrict__ out) {
  const int b = blockIdx.x;
  const int tid = threadIdx.x;
  const int lane = tid & 63;
  const int wave = tid >> 6;
  __shared__ float rs_[4], rq_[4], rp_[4];

  const ushort4 xv = ((const ushort4*)(X + (size_t)b * HDIM))[tid];
  const float x0 = bf2f(xv.x), x1 = bf2f(xv.y), x2 = bf2f(xv.z), x3 = bf2f(xv.w);
  float s = x0 + x1 + x2 + x3;
  float q = x0 * x0 + x1 * x1 + x2 * x2 + x3 * x3;
  #pragma unroll
  for (int off = 32; off; off >>= 1) {
    s += __shfl_xor(s, off);
    q += __shfl_xor(q, off);
  }
  if (lane == 0) { rs_[wave] = s; rq_[wave] = q; }
  __syncthreads();
  s = rs_[0] + rs_[1] + rs_[2] + rs_[3];
  q = rq_[0] + rq_[1] + rq_[2] + rq_[3];
  const float mu = s * (1.0f / 1024.0f);
  const float var = q * (1.0f / 1024.0f) - mu * mu;
  const float rsig = rsqrtf(var + 1e-5f);

  const float4 gv = ((const float4*)g)[tid];
  const float4 bv = ((const float4*)bta)[tid];
  const float y0 = fmaxf((x0 - mu) * rsig * gv.x + bv.x, 0.0f);
  const float y1 = fmaxf((x1 - mu) * rsig * gv.y + bv.y, 0.0f);
  const float y2 = fmaxf((x2 - mu) * rsig * gv.z + bv.z, 0.0f);
  const float y3 = fmaxf((x3 - mu) * rsig * gv.w + bv.w, 0.0f);

  if constexpr (!HEAD) {
    ushort4 o;
    o.x = f2bf(y0); o.y = f2bf(y1); o.z = f2bf(y2); o.w = f2bf(y3);
    ((ushort4*)(Y + (size_t)b * HDIM))[tid] = o;
  } else {
    const float4 wv = ((const float4*)Wh)[tid];
    float p = y0 * wv.x + y1 * wv.y + y2 * wv.z + y3 * wv.w;
    #pragma unroll
    for (int off = 32; off; off >>= 1) p += __shfl_xor(p, off);
    if (lane == 0) rp_[wave] = p;
    __syncthreads();
    if (tid < 64) {
      const float qf = rp_[0] + rp_[1] + rp_[2] + rp_[3];
      out[(size_t)b * NQD + tid] = qf + qt[tid];
    }
  }
}

// ---------------- launch ----------------

extern "C" void kernel_launch(void* const* d_in, const int* in_sizes, int n_in,
                              void* d_out, int out_size, void* d_ws, size_t ws_size,
                              hipStream_t stream) {
  (void)in_sizes; (void)n_in; (void)out_size; (void)ws_size;
  const float* state  = (const float*)d_in[0];
  const float* action = (const float*)d_in[1];
  const float* We1 = (const float*)d_in[2];
  const float* be1 = (const float*)d_in[3];
  const float* We2 = (const float*)d_in[4];
  const float* be2 = (const float*)d_in[5];
  const float* Wf1 = (const float*)d_in[6];
  const float* bW1 = (const float*)d_in[7];
  const float* g1  = (const float*)d_in[8];
  const float* bt1 = (const float*)d_in[9];
  const float* Wf2 = (const float*)d_in[10];
  const float* bW2 = (const float*)d_in[11];
  const float* g2  = (const float*)d_in[12];
  const float* bt2 = (const float*)d_in[13];
  const float* Wh  = (const float*)d_in[14];
  const float* bh  = (const float*)d_in[15];
  float* out = (float*)d_out;

  char* ws = (char*)d_ws;
  unsigned short* xb   = (unsigned short*)(ws);               // BATCH*576 bf16
  unsigned short* w1b  = (unsigned short*)(ws + 18874368);    // 2*1024*576 bf16
  unsigned short* w2b  = (unsigned short*)(ws + 21233664);    // 2*1024*1024 bf16
  float*          qtw  = (float*)(ws + 25427968);             // 2*64 f32
  unsigned short* ha   = (unsigned short*)(ws + 25428480);    // BATCH*1024 bf16
  unsigned short* hb   = (unsigned short*)(ws + 58982912);    // BATCH*1024 bf16

  cvt_x<<<2048, 256, 0, stream>>>(state, action, xb);
  cvt_w<<<1024, 256, 0, stream>>>(Wf1, w1b, 2 * HDIM * XDIM / 4);
  cvt_w<<<1024, 256, 0, stream>>>(Wf2, w2b, 2 * HDIM * HDIM / 4);
  qtau_kernel<<<128, 64, 0, stream>>>(We1, be1, We2, be2, Wh, bh, qtw);

  for (int c = 0; c < 2; ++c) {
    gemm256<XDIM><<<256, 512, 0, stream>>>(
        xb, w1b + (size_t)c * HDIM * XDIM, bW1 + c * HDIM, ha);
    ln_head<false><<<BATCH, 256, 0, stream>>>(
        ha, g1 + c * HDIM, bt1 + c * HDIM, hb, nullptr, nullptr, nullptr);
    gemm256<HDIM><<<256, 512, 0, stream>>>(
        hb, w2b + (size_t)c * HDIM * HDIM, bW2 + c * HDIM, ha);
    ln_head<true><<<BATCH, 256, 0, stream>>>(
        ha, g2 + c * HDIM, bt2 + c * HDIM, nullptr,
        Wh + (size_t)c * (HDIM + QED), qtw + c * 64, out + (size_t)c * BATCH * NQD);
  }
}

// Round 4
// 203.160 us; speedup vs baseline: 1.0396x; 1.0396x over previous
//
#include <hip/hip_runtime.h>
#include <stdint.h>

#define BATCH 16384
#define SDIM 512
#define ADIM 64
#define XDIM 576      // SDIM + ADIM
#define HDIM 1024
#define NQD 64
#define QED 64

typedef __attribute__((ext_vector_type(8))) short short8;
typedef __attribute__((ext_vector_type(4))) float f32x4;

static __device__ inline unsigned short f2bf(float f) {
  unsigned int u = __float_as_uint(f);
  unsigned int r = (u + 0x7fffu + ((u >> 16) & 1u)) >> 16;
  return (unsigned short)r;
}
static __device__ inline float bf2f(unsigned short u) {
  return __uint_as_float(((unsigned int)u) << 16);
}

static __device__ inline void gload_lds16(const void* g, void* l) {
  __builtin_amdgcn_global_load_lds(
      (const __attribute__((address_space(1))) uint32_t*)g,
      (__attribute__((address_space(3))) uint32_t*)l, 16, 0, 0);
}

#define FENCE() asm volatile("" ::: "memory")

// ---------------- conversion kernels ----------------

__global__ __launch_bounds__(256) void cvt_x(const float* __restrict__ st,
                                             const float* __restrict__ ac,
                                             unsigned short* __restrict__ xb) {
  const int total = BATCH * XDIM / 4;
  for (int i = blockIdx.x * blockDim.x + threadIdx.x; i < total;
       i += gridDim.x * blockDim.x) {
    const int e = i * 4;
    const int b = e / XDIM;
    const int j = e - b * XDIM;
    float4 v;
    if (j < SDIM) v = *(const float4*)(st + (size_t)b * SDIM + j);
    else          v = *(const float4*)(ac + (size_t)b * ADIM + (j - SDIM));
    ushort4 o;
    o.x = f2bf(v.x); o.y = f2bf(v.y); o.z = f2bf(v.z); o.w = f2bf(v.w);
    ((ushort4*)xb)[i] = o;
  }
}

__global__ __launch_bounds__(256) void cvt_w(const float* __restrict__ src,
                                             unsigned short* __restrict__ dst, int n4) {
  for (int i = blockIdx.x * blockDim.x + threadIdx.x; i < n4;
       i += gridDim.x * blockDim.x) {
    const float4 v = ((const float4*)src)[i];
    ushort4 o;
    o.x = f2bf(v.x); o.y = f2bf(v.y); o.z = f2bf(v.z); o.w = f2bf(v.w);
    ((ushort4*)dst)[i] = o;
  }
}

// ---------------- tau embedding head contribution (exact fp32) ----------------

__global__ void qtau_kernel(const float* __restrict__ We1, const float* __restrict__ be1,
                            const float* __restrict__ We2, const float* __restrict__ be2,
                            const float* __restrict__ Wh,  const float* __restrict__ bh,
                            float* __restrict__ qtau) {
  const int c = blockIdx.x >> 6;
  const int nq = blockIdx.x & 63;
  const int q = threadIdx.x;  // 64 threads = 1 wave
  const float tau = (float)nq / 64.0f + 0.0078125f;
  float acc = be2[c * 64 + q];
  for (int e = 0; e < 64; ++e) {
    const float t1 = fmaxf(tau * We1[c * 64 + e] + be1[c * 64 + e], 0.0f);
    acc += t1 * We2[(c * 64 + q) * 64 + e];
  }
  float v = acc * Wh[c * (HDIM + QED) + HDIM + q];
  #pragma unroll
  for (int off = 32; off; off >>= 1) v += __shfl_xor(v, off);
  if (q == 0) qtau[c * 64 + nq] = v + bh[c];
}

// ---------------- 256x256 bf16 GEMM, 2 barriers/tile, counted waits --------
// C[M,1024] = A[M,K] * W[1024,K]^T + bias, bf16 in/out, fp32 accum.
// 8 waves (2M x 4N), BK=64. All 24 frag ds_reads issue at tile top; MFMAs
// q0/q1 consume the first frags under counted lgkmcnt while b1/a1 reads
// complete in their shadow. One mid-tile barrier (stage-into-current-buf
// safety), q2/q3 run register-only overlapping the t+2 half-stages. Counted
// vmcnt(4) at the tile boundary only (never 0 mid-loop).

template <int K>
__global__ __launch_bounds__(512, 2) void gemm256(const unsigned short* __restrict__ A,
                                                  const unsigned short* __restrict__ W,
                                                  const float* __restrict__ bias,
                                                  unsigned short* __restrict__ C) {
  constexpr int NT = K / 64;
  __shared__ unsigned short Asm[2][256][64];
  __shared__ unsigned short Bsm[2][256][64];

  const int tid  = threadIdx.x;
  const int lane = tid & 63;
  const int wave = tid >> 6;
  const int wm = wave >> 2;   // 0..1
  const int wn = wave & 3;    // 0..3

  // XCD-bijective swizzle: 256 blocks, 8 XCDs, 32 contiguous logical per XCD.
  const int L = (int)blockIdx.x;
  const int logical = (L & 7) * 32 + (L >> 3);
  const int mBase = (logical >> 2) * 256;
  const int nBase = (logical & 3) * 256;

  // staging geometry: per half-tile (128x64) each wave writes 2 x 1KB chunks
  const int c0 = wave * 2;
  const int srow  = lane >> 3;                 // 0..7 within chunk
  const int sslot = (lane & 7) ^ (lane >> 3);  // inverse-swizzled source slot

  auto stageA = [&](int buf, int h, int kt) {
    const unsigned short* s =
        A + (size_t)(mBase + h * 128 + c0 * 8 + srow) * K + kt * 64 + sslot * 8;
    gload_lds16(s, &Asm[buf][h * 128 + c0 * 8][0]);
    gload_lds16(s + (size_t)8 * K, &Asm[buf][h * 128 + c0 * 8 + 8][0]);
  };
  auto stageB = [&](int buf, int h, int kt) {
    const unsigned short* s =
        W + (size_t)(nBase + h * 128 + c0 * 8 + srow) * K + kt * 64 + sslot * 8;
    gload_lds16(s, &Bsm[buf][h * 128 + c0 * 8][0]);
    gload_lds16(s + (size_t)8 * K, &Bsm[buf][h * 128 + c0 * 8 + 8][0]);
  };

  auto ldA = [&](short8* d, int buf, int mh) {
    #pragma unroll
    for (int fm = 0; fm < 4; ++fm)
      #pragma unroll
      for (int ks = 0; ks < 2; ++ks) {
        const int r = mh * 128 + wm * 64 + fm * 16 + (lane & 15);
        const int ps = (ks * 4 + (lane >> 4)) ^ (r & 7);
        d[fm * 2 + ks] = *(const short8*)&Asm[buf][r][ps * 8];
      }
  };
  auto ldB = [&](short8* d, int buf, int nhalf) {
    #pragma unroll
    for (int fn = 0; fn < 2; ++fn)
      #pragma unroll
      for (int ks = 0; ks < 2; ++ks) {
        const int r = nhalf * 128 + wn * 32 + fn * 16 + (lane & 15);
        const int ps = (ks * 4 + (lane >> 4)) ^ (r & 7);
        d[fn * 2 + ks] = *(const short8*)&Bsm[buf][r][ps * 8];
      }
  };

  f32x4 acc[4][4][2];
  #pragma unroll
  for (int q = 0; q < 4; ++q)
    #pragma unroll
    for (int fm = 0; fm < 4; ++fm)
      #pragma unroll
      for (int fn = 0; fn < 2; ++fn) {
        f32x4 z = {0.f, 0.f, 0.f, 0.f};
        acc[q][fm][fn] = z;
      }

  auto mfmaQ = [&](f32x4 (&aq)[4][2], short8* a, short8* b) {
    #pragma unroll
    for (int fm = 0; fm < 4; ++fm)
      #pragma unroll
      for (int fn = 0; fn < 2; ++fn)
        #pragma unroll
        for (int ks = 0; ks < 2; ++ks)
          aq[fm][fn] = __builtin_amdgcn_mfma_f32_16x16x32_bf16(
              a[fm * 2 + ks], b[fn * 2 + ks], aq[fm][fn], 0, 0, 0);
  };

  short8 a0[8], a1[8], b0[4], b1[4];

  // prologue: tile0 fully + Ah0(1), Bh0(1) (steady-state stream positions)
  stageA(0, 0, 0); stageA(0, 1, 0); stageB(0, 0, 0); stageB(0, 1, 0);
  if (NT > 1) { stageA(1, 0, 1); stageB(1, 0, 1); }
  FENCE();
  if (NT > 1) asm volatile("s_waitcnt vmcnt(4)" ::: "memory");
  else        asm volatile("s_waitcnt vmcnt(0)" ::: "memory");
  __builtin_amdgcn_s_barrier();
  FENCE();

  for (int t = 0; t < NT; ++t) {
    const int buf = t & 1;
    // ---- region A: all frag reads up front; h1 stages for t+1; q0,q1 ----
    ldA(a0, buf, 0);
    ldB(b0, buf, 0);
    ldB(b1, buf, 1);
    ldA(a1, buf, 1);
    if (t + 1 < NT) { stageA(buf ^ 1, 1, t + 1); stageB(buf ^ 1, 1, t + 1); }
    __builtin_amdgcn_s_setprio(1);
    mfmaQ(acc[0], a0, b0);   // waits only a0,b0 (counted lgkm); b1,a1 in flight
    mfmaQ(acc[1], a0, b1);
    __builtin_amdgcn_s_setprio(0);
    FENCE(); __builtin_amdgcn_s_barrier(); FENCE();
    // ---- region B: h0 stages for t+2 into current buf; q2,q3 reg-only ----
    if (t + 2 < NT) { stageA(buf, 0, t + 2); stageB(buf, 0, t + 2); }
    __builtin_amdgcn_s_setprio(1);
    mfmaQ(acc[2], a1, b1);
    mfmaQ(acc[3], a1, b0);
    __builtin_amdgcn_s_setprio(0);
    if (t + 1 < NT) {
      FENCE();
      if (t >= NT - 2) asm volatile("s_waitcnt vmcnt(0)" ::: "memory");
      else             asm volatile("s_waitcnt vmcnt(4)" ::: "memory");
      __builtin_amdgcn_s_barrier();
      FENCE();
    }
  }

  // epilogue: bias + bf16 round + store
  const int MH[4] = {0, 0, 1, 1};
  const int NH[4] = {0, 1, 1, 0};
  #pragma unroll
  for (int q = 0; q < 4; ++q)
    #pragma unroll
    for (int fm = 0; fm < 4; ++fm)
      #pragma unroll
      for (int fn = 0; fn < 2; ++fn) {
        const int col = nBase + NH[q] * 128 + wn * 32 + fn * 16 + (lane & 15);
        const int row0 = mBase + MH[q] * 128 + wm * 64 + fm * 16 + (lane >> 4) * 4;
        const float bv = bias[col];
        #pragma unroll
        for (int j = 0; j < 4; ++j)
          C[(size_t)(row0 + j) * HDIM + col] = f2bf(acc[q][fm][fn][j] + bv);
      }
}

// ---------------- row LayerNorm + ReLU (+ optional fused head) ----------------

template <bool HEAD>
__global__ __launch_bounds__(256) void ln_head(const unsigned short* __restrict__ X,
                                               const float* __restrict__ g,
                                               const float* __restrict__ bta,
                                               unsigned short* __restrict__ Y,
                                               const float* __restrict__ Wh,
                                               const float* __restrict__ qt,
                                               float* __restrict__ out) {
  const int b = blockIdx.x;
  const int tid = threadIdx.x;
  const int lane = tid & 63;
  const int wave = tid >> 6;
  __shared__ float rs_[4], rq_[4], rp_[4];

  const ushort4 xv = ((const ushort4*)(X + (size_t)b * HDIM))[tid];
  const float x0 = bf2f(xv.x), x1 = bf2f(xv.y), x2 = bf2f(xv.z), x3 = bf2f(xv.w);
  float s = x0 + x1 + x2 + x3;
  float q = x0 * x0 + x1 * x1 + x2 * x2 + x3 * x3;
  #pragma unroll
  for (int off = 32; off; off >>= 1) {
    s += __shfl_xor(s, off);
    q += __shfl_xor(q, off);
  }
  if (lane == 0) { rs_[wave] = s; rq_[wave] = q; }
  __syncthreads();
  s = rs_[0] + rs_[1] + rs_[2] + rs_[3];
  q = rq_[0] + rq_[1] + rq_[2] + rq_[3];
  const float mu = s * (1.0f / 1024.0f);
  const float var = q * (1.0f / 1024.0f) - mu * mu;
  const float rsig = rsqrtf(var + 1e-5f);

  const float4 gv = ((const float4*)g)[tid];
  const float4 bv = ((const float4*)bta)[tid];
  const float y0 = fmaxf((x0 - mu) * rsig * gv.x + bv.x, 0.0f);
  const float y1 = fmaxf((x1 - mu) * rsig * gv.y + bv.y, 0.0f);
  const float y2 = fmaxf((x2 - mu) * rsig * gv.z + bv.z, 0.0f);
  const float y3 = fmaxf((x3 - mu) * rsig * gv.w + bv.w, 0.0f);

  if constexpr (!HEAD) {
    ushort4 o;
    o.x = f2bf(y0); o.y = f2bf(y1); o.z = f2bf(y2); o.w = f2bf(y3);
    ((ushort4*)(Y + (size_t)b * HDIM))[tid] = o;
  } else {
    const float4 wv = ((const float4*)Wh)[tid];
    float p = y0 * wv.x + y1 * wv.y + y2 * wv.z + y3 * wv.w;
    #pragma unroll
    for (int off = 32; off; off >>= 1) p += __shfl_xor(p, off);
    if (lane == 0) rp_[wave] = p;
    __syncthreads();
    if (tid < 64) {
      const float qf = rp_[0] + rp_[1] + rp_[2] + rp_[3];
      out[(size_t)b * NQD + tid] = qf + qt[tid];
    }
  }
}

// ---------------- launch ----------------

extern "C" void kernel_launch(void* const* d_in, const int* in_sizes, int n_in,
                              void* d_out, int out_size, void* d_ws, size_t ws_size,
                              hipStream_t stream) {
  (void)in_sizes; (void)n_in; (void)out_size; (void)ws_size;
  const float* state  = (const float*)d_in[0];
  const float* action = (const float*)d_in[1];
  const float* We1 = (const float*)d_in[2];
  const float* be1 = (const float*)d_in[3];
  const float* We2 = (const float*)d_in[4];
  const float* be2 = (const float*)d_in[5];
  const float* Wf1 = (const float*)d_in[6];
  const float* bW1 = (const float*)d_in[7];
  const float* g1  = (const float*)d_in[8];
  const float* bt1 = (const float*)d_in[9];
  const float* Wf2 = (const float*)d_in[10];
  const float* bW2 = (const float*)d_in[11];
  const float* g2  = (const float*)d_in[12];
  const float* bt2 = (const float*)d_in[13];
  const float* Wh  = (const float*)d_in[14];
  const float* bh  = (const float*)d_in[15];
  float* out = (float*)d_out;

  char* ws = (char*)d_ws;
  unsigned short* xb   = (unsigned short*)(ws);               // BATCH*576 bf16
  unsigned short* w1b  = (unsigned short*)(ws + 18874368);    // 2*1024*576 bf16
  unsigned short* w2b  = (unsigned short*)(ws + 21233664);    // 2*1024*1024 bf16
  float*          qtw  = (float*)(ws + 25427968);             // 2*64 f32
  unsigned short* ha   = (unsigned short*)(ws + 25428480);    // BATCH*1024 bf16
  unsigned short* hb   = (unsigned short*)(ws + 58982912);    // BATCH*1024 bf16

  cvt_x<<<2048, 256, 0, stream>>>(state, action, xb);
  cvt_w<<<1024, 256, 0, stream>>>(Wf1, w1b, 2 * HDIM * XDIM / 4);
  cvt_w<<<1024, 256, 0, stream>>>(Wf2, w2b, 2 * HDIM * HDIM / 4);
  qtau_kernel<<<128, 64, 0, stream>>>(We1, be1, We2, be2, Wh, bh, qtw);

  for (int c = 0; c < 2; ++c) {
    gemm256<XDIM><<<256, 512, 0, stream>>>(
        xb, w1b + (size_t)c * HDIM * XDIM, bW1 + c * HDIM, ha);
    ln_head<false><<<BATCH, 256, 0, stream>>>(
        ha, g1 + c * HDIM, bt1 + c * HDIM, hb, nullptr, nullptr, nullptr);
    gemm256<HDIM><<<256, 512, 0, stream>>>(
        hb, w2b + (size_t)c * HDIM * HDIM, bW2 + c * HDIM, ha);
    ln_head<true><<<BATCH, 256, 0, stream>>>(
        ha, g2 + c * HDIM, bt2 + c * HDIM, nullptr,
        Wh + (size_t)c * (HDIM + QED), qtw + c * 64, out + (size_t)c * BATCH * NQD);
  }
}